// Round 6
// baseline (242.809 us; speedup 1.0000x reference)
//
#include <hip/hip_runtime.h>
#include <hip/hip_bf16.h>

#define DD 256
#define BB 2048
#define BM 256                   // one full i per block: all 256 j-rows
#define BN 64                    // batch columns per pipeline stage
#define NTILE 256                // one block per i -> exactly 1 block/CU
#define NSTAGE (BB / BN)         // 32 pipeline iterations

typedef __bf16 bf16x8 __attribute__((ext_vector_type(8)));
typedef float  f32x4  __attribute__((ext_vector_type(4)));

#define AS1 __attribute__((address_space(1)))
#define AS3 __attribute__((address_space(3)))

__device__ __forceinline__ unsigned short f2bf(float f) {
    unsigned int u = __float_as_uint(f);
    return (unsigned short)((u + 0x7FFFu + ((u >> 16) & 1u)) >> 16);  // RNE
}
__device__ __forceinline__ float bf2f(unsigned short s) {
    return __uint_as_float(((unsigned int)s) << 16);
}
__device__ __forceinline__ void async_cp16(const void* g, void* l) {
    __builtin_amdgcn_global_load_lds((const AS1 unsigned int*)g,
                                     (AS3 unsigned int*)l, 16, 0, 0);
}

// K1: rel = x - offsets -> bf16 (all downstream consumers) and out[b] = c0 + <c1, rel_b>
__global__ void prep_all(const float* __restrict__ x, const float* __restrict__ offsets,
                         const float* __restrict__ c0, const float* __restrict__ c1,
                         unsigned short* __restrict__ rel_bf16, float* __restrict__ out) {
    const int tid = threadIdx.x, wave = tid >> 6, lane = tid & 63;
    const float4 o4  = *(const float4*)(offsets + lane * 4);
    const float4 c14 = *(const float4*)(c1 + lane * 4);
#pragma unroll
    for (int i = 0; i < 2; ++i) {
        const int b = blockIdx.x * 8 + wave * 2 + i;
        const float4 x4 = *(const float4*)(x + (size_t)b * DD + lane * 4);
        float4 r;
        r.x = x4.x - o4.x; r.y = x4.y - o4.y; r.z = x4.z - o4.z; r.w = x4.w - o4.w;
        ushort4 rb;
        rb.x = f2bf(r.x); rb.y = f2bf(r.y); rb.z = f2bf(r.z); rb.w = f2bf(r.w);
        *(ushort4*)(rel_bf16 + (size_t)b * DD + lane * 4) = rb;
        float s = r.x * c14.x + r.y * c14.y + r.z * c14.z + r.w * c14.w;
        s += __shfl_xor(s, 1);  s += __shfl_xor(s, 2);  s += __shfl_xor(s, 4);
        s += __shfl_xor(s, 8);  s += __shfl_xor(s, 16); s += __shfl_xor(s, 32);
        if (lane == 0) out[b] = c0[0] + s;
    }
}

// K3: fused GEMM (c3[i,:,:] @ rel^T) + c2 fold + weighted column reduction.
// One block per i (256 blocks, 1024 threads = 16 waves, exactly 1 block/CU).
// Waves: wm(4: 64 j-rows) x wk(2: 128-k halves) x wn(2: 32-col halves).
// Each staged B-tile (32 KB) is amortized over 256 j-rows (2x R0) -> grid staging
// halves to 256 MB. Per-wave regs: afr[4][4]=64 + acc[4][2]=32 (R5-proven: 104 VGPR,
// no spill) under launch_bounds(1024,4)'s 128-reg cap -> 16 waves/CU = 4 waves/SIMD.
__global__ __launch_bounds__(1024, 4) void taylor3(
    const float* __restrict__ c3, const float* __restrict__ c2,
    const unsigned short* __restrict__ rel_bf16, float* __restrict__ partial)
{
    __shared__ unsigned short Bs[2][BN * DD];          // 64 KB, double-buffered
    __shared__ unsigned short relIbf[BB];              // 4 KB: rel[:, i_t] bf16
    __shared__ __align__(16) float c2row[DD];          // 1 KB: c2[i_t, :]
    __shared__ float colsum[2][8][BN];                 // 4 KB, per-(wk,wm) partials, dbuf

    const int i_t  = blockIdx.x;
    const int tid  = threadIdx.x;
    const int wave = tid >> 6;
    const int lane = tid & 63;
    const int wm = wave & 3, wk = (wave >> 2) & 1, wn = wave >> 3;
    const int lrow = lane & 15, quad = lane >> 4;

    // stage rel[:, i_t] (bf16) into LDS, one-time
#pragma unroll
    for (int k = 0; k < 2; ++k) {
        const int b = tid + k * 1024;
        relIbf[b] = rel_bf16[(size_t)b * DD + i_t];
    }
    if (tid < DD) c2row[tid] = c2[i_t * DD + tid];

    // ---- async stage: tile nb -> Bs[buf]; 2 rounds x 32 rows, swizzled granules ----
    auto stage = [&](int nb, int buf) {
        const int b0 = nb * BN;
#pragma unroll
        for (int c = 0; c < 2; ++c) {
            const int r0 = c * 32 + wave * 2;           // wave-uniform base row (0..63)
            const int row = r0 + (lane >> 5);
            const int g = (lane & 31) ^ (row & 7);      // logical granule for this phys slot
            const unsigned short* src = rel_bf16 + (size_t)(b0 + row) * DD + g * 8;
            async_cp16(src, &Bs[buf][r0 * DD]);
        }
    };

    stage(0, 0);   // issue first prefetch before the afr hoist covers its latency

    // ---- hoist A fragments: 64 j-rows (mt=4) x own 128-k half -> 64 VGPRs ----
    bf16x8 afr[4][4];
    {
        const float* abase = c3 + (size_t)i_t * DD * DD;
#pragma unroll
        for (int mt = 0; mt < 4; ++mt) {
            const int j = wm * 64 + mt * 16 + lrow;
            const float* p = abase + (size_t)j * DD + wk * 128 + quad * 8;
#pragma unroll
            for (int ks = 0; ks < 4; ++ks) {
                const float4 f0 = *(const float4*)(p + ks * 32);
                const float4 f1 = *(const float4*)(p + ks * 32 + 4);
                union { unsigned short u[8]; bf16x8 v; } cv;
                cv.u[0] = f2bf(f0.x); cv.u[1] = f2bf(f0.y);
                cv.u[2] = f2bf(f0.z); cv.u[3] = f2bf(f0.w);
                cv.u[4] = f2bf(f1.x); cv.u[5] = f2bf(f1.y);
                cv.u[6] = f2bf(f1.z); cv.u[7] = f2bf(f1.w);
                afr[ks][mt] = cv.v;
            }
        }
    }

    // ---- one pipeline stage; cur is a compile-time literal at each call site ----
    auto body = [&](int nb, int cur) {
        const int b0 = nb * BN;
        __syncthreads();          // drains async loads of Bs[cur]; WAR-protects Bs[cur^1]
        if (nb + 1 < NSTAGE) stage(nb + 1, cur ^ 1);

        // combine previous stage's colsum (parity cur^1); plain coalesced store (wave 0)
        if (nb > 0 && wave == 0) {
            const int pb0 = b0 - BN;
            float v = colsum[cur ^ 1][0][lane];
#pragma unroll
            for (int w = 1; w < 8; ++w) v += colsum[cur ^ 1][w][lane];
            partial[(size_t)i_t * BB + pb0 + lane] = bf2f(relIbf[pb0 + lane]) * v;
        }

        f32x4 acc[4][2];
        __builtin_amdgcn_s_setprio(1);
        // ---- K-loop: 4 steps of 16x16x32 over this wave's 128-k half; ks=0 peeled ----
        {
            const int glog = wk * 16 + quad;
            bf16x8 bfr[2];
#pragma unroll
            for (int nt = 0; nt < 2; ++nt) {
                const int col = wn * 32 + nt * 16 + lrow;
                const int g = glog ^ (col & 7);
                bfr[nt] = *(const bf16x8*)(&Bs[cur][col * DD + g * 8]);
            }
            const f32x4 z4 = (f32x4){0.f, 0.f, 0.f, 0.f};
#pragma unroll
            for (int mt = 0; mt < 4; ++mt)
#pragma unroll
                for (int nt = 0; nt < 2; ++nt)
                    acc[mt][nt] = __builtin_amdgcn_mfma_f32_16x16x32_bf16(
                        afr[0][mt], bfr[nt], z4, 0, 0, 0);
        }
#pragma unroll
        for (int ks = 1; ks < 4; ++ks) {
            const int glog = wk * 16 + ks * 4 + quad;
            bf16x8 bfr[2];
#pragma unroll
            for (int nt = 0; nt < 2; ++nt) {
                const int col = wn * 32 + nt * 16 + lrow;
                const int g = glog ^ (col & 7);
                bfr[nt] = *(const bf16x8*)(&Bs[cur][col * DD + g * 8]);
            }
#pragma unroll
            for (int mt = 0; mt < 4; ++mt)
#pragma unroll
                for (int nt = 0; nt < 2; ++nt)
                    acc[mt][nt] = __builtin_amdgcn_mfma_f32_16x16x32_bf16(
                        afr[ks][mt], bfr[nt], acc[mt][nt], 0, 0, 0);
        }
        __builtin_amdgcn_s_setprio(0);

        // ---- epilogue: s(col) = sum_rows (G + c2?) * r[b, j(row)]; indep chains ----
        float sv[2];
#pragma unroll
        for (int nt = 0; nt < 2; ++nt) {
            const int col = wn * 32 + nt * 16 + lrow;
            float s0 = 0.f, s1 = 0.f;
#pragma unroll
            for (int mt = 0; mt < 4; ++mt) {
                const int e = wm * 64 + mt * 16 + quad * 4;     // global j, 4-aligned
                const int g = (e >> 3) ^ (col & 7);
                const ushort4 rj = *(const ushort4*)(&Bs[cur][col * DD + g * 8 + (e & 7)]);
                f32x4 a = acc[mt][nt];
                if (wk == 0) {   // c2 folded exactly once per (j, col), wave-uniform branch
                    const float4 c2r = *(const float4*)(&c2row[e]);
                    a[0] += c2r.x; a[1] += c2r.y; a[2] += c2r.z; a[3] += c2r.w;
                }
                float& sa = (mt & 1) ? s1 : s0;   // mt is compile-time constant
                sa = fmaf(a[0], bf2f(rj.x), sa);
                sa = fmaf(a[1], bf2f(rj.y), sa);
                sa = fmaf(a[2], bf2f(rj.z), sa);
                sa = fmaf(a[3], bf2f(rj.w), sa);
            }
            float s = s0 + s1;
            s += __shfl_xor(s, 16, 64);
            s += __shfl_xor(s, 32, 64);   // all lanes hold the column total
            sv[nt] = s;
        }
        // lanes 0..31 write this wave's 32 columns (wn selects the half)
        if (lane < 32)
            colsum[cur][wk * 4 + wm][wn * 32 + lane] = (lane & 16) ? sv[1] : sv[0];
    };

    for (int nb = 0; nb < NSTAGE; nb += 2) {
        body(nb, 0);
        body(nb + 1, 1);
    }

    __syncthreads();
    if (wave == 0) {   // final combine, parity (NSTAGE-1)&1 = 1
        const int pb0 = BB - BN;
        float v = colsum[1][0][lane];
#pragma unroll
        for (int w = 1; w < 8; ++w) v += colsum[1][w][lane];
        partial[(size_t)i_t * BB + pb0 + lane] = bf2f(relIbf[pb0 + lane]) * v;
    }
}

// K4: out[b] += sum over 256 partial rows. 128 blocks x 256 threads.
__global__ void reduce_partial(const float* __restrict__ partial, float* __restrict__ out) {
    __shared__ f32x4 red[256];
    const int t = threadIdx.x;
    const int g = blockIdx.x * 4 + (t & 3);   // float4 column group (512 total)
    const int slice = t >> 2;                 // 64 row-slices of 4 rows (256 total)
    f32x4 s = (f32x4){0.f, 0.f, 0.f, 0.f};
    for (int r = slice * 4; r < slice * 4 + 4; ++r)
        s += *(const f32x4*)(partial + (size_t)r * BB + g * 4);
    red[t] = s; __syncthreads();
    if (t < 128) red[t] += red[t + 128]; __syncthreads();
    if (t < 64)  red[t] += red[t + 64];  __syncthreads();
    if (t < 32)  red[t] += red[t + 32];  __syncthreads();
    if (t < 16)  red[t] += red[t + 16];  __syncthreads();
    if (t < 8)   red[t] += red[t + 8];   __syncthreads();
    if (t < 4) {
        const f32x4 v = red[t] + red[t + 4];
        float4* op = (float4*)(out + (size_t)(blockIdx.x * 4 + t) * 4);
        float4 o = *op;
        o.x += v[0]; o.y += v[1]; o.z += v[2]; o.w += v[3];
        *op = o;
    }
}

extern "C" void kernel_launch(void* const* d_in, const int* in_sizes, int n_in,
                              void* d_out, int out_size, void* d_ws, size_t ws_size,
                              hipStream_t stream) {
    const float* x       = (const float*)d_in[0];
    const float* offsets = (const float*)d_in[1];
    const float* c0      = (const float*)d_in[2];
    const float* c1      = (const float*)d_in[3];
    const float* c2      = (const float*)d_in[4];
    const float* c3      = (const float*)d_in[5];
    float* out = (float*)d_out;

    char* ws = (char*)d_ws;
    unsigned short* rel_bf16 = (unsigned short*)ws;                      // 1 MB
    float* partial = (float*)(ws + (size_t)1 * 1024 * 1024);             // 2 MB (256 x 2048)

    prep_all<<<BB / 8, 256, 0, stream>>>(x, offsets, c0, c1, rel_bf16, out);
    taylor3<<<NTILE, 1024, 0, stream>>>(c3, c2, rel_bf16, partial);
    reduce_partial<<<128, 256, 0, stream>>>(partial, out);
}

// Round 7
// 196.481 us; speedup vs baseline: 1.2358x; 1.2358x over previous
//
#include <hip/hip_runtime.h>
#include <hip/hip_bf16.h>

#define DD 256
#define BB 2048
#define BM 128                   // c3 rows per block tile (j-half of one i)
#define BN 32                    // batch columns per pipeline stage
#define NTILE 512                // 256 i x 2 j-halves -> exactly 2 blocks/CU
#define NSTAGE (BB / BN)         // 64 pipeline iterations

typedef __bf16 bf16x8 __attribute__((ext_vector_type(8)));
typedef float  f32x4  __attribute__((ext_vector_type(4)));

#define AS1 __attribute__((address_space(1)))
#define AS3 __attribute__((address_space(3)))

__device__ __forceinline__ unsigned short f2bf(float f) {
    unsigned int u = __float_as_uint(f);
    return (unsigned short)((u + 0x7FFFu + ((u >> 16) & 1u)) >> 16);  // RNE
}
__device__ __forceinline__ float bf2f(unsigned short s) {
    return __uint_as_float(((unsigned int)s) << 16);
}
__device__ __forceinline__ void async_cp16(const void* g, void* l) {
    __builtin_amdgcn_global_load_lds((const AS1 unsigned int*)g,
                                     (AS3 unsigned int*)l, 16, 0, 0);
}

// K1: rel = x - offsets -> bf16 (all downstream consumers) and out[b] = c0 + <c1, rel_b>
__global__ void prep_all(const float* __restrict__ x, const float* __restrict__ offsets,
                         const float* __restrict__ c0, const float* __restrict__ c1,
                         unsigned short* __restrict__ rel_bf16, float* __restrict__ out) {
    const int tid = threadIdx.x, wave = tid >> 6, lane = tid & 63;
    const float4 o4  = *(const float4*)(offsets + lane * 4);
    const float4 c14 = *(const float4*)(c1 + lane * 4);
#pragma unroll
    for (int i = 0; i < 2; ++i) {
        const int b = blockIdx.x * 8 + wave * 2 + i;
        const float4 x4 = *(const float4*)(x + (size_t)b * DD + lane * 4);
        float4 r;
        r.x = x4.x - o4.x; r.y = x4.y - o4.y; r.z = x4.z - o4.z; r.w = x4.w - o4.w;
        ushort4 rb;
        rb.x = f2bf(r.x); rb.y = f2bf(r.y); rb.z = f2bf(r.z); rb.w = f2bf(r.w);
        *(ushort4*)(rel_bf16 + (size_t)b * DD + lane * 4) = rb;
        float s = r.x * c14.x + r.y * c14.y + r.z * c14.z + r.w * c14.w;
        s += __shfl_xor(s, 1);  s += __shfl_xor(s, 2);  s += __shfl_xor(s, 4);
        s += __shfl_xor(s, 8);  s += __shfl_xor(s, 16); s += __shfl_xor(s, 32);
        if (lane == 0) out[b] = c0[0] + s;
    }
}

// K3: fused GEMM (c3 j-half tile @ rel^T) + c2 fold + weighted column reduction.
// 512 blocks (i x j-half) x 512 threads = 8 waves: wm(2: 64 rows) x wk(4: 64-k quarters).
// Per wave: afr[2][4]=32 regs (proven no-spill shape), acc[4][2]=32, 16 MFMA/wave-stage.
// LDS 39.4 KB; grid = exactly 2 blocks/CU -> 16 waves/CU = 4 waves/SIMD (2x R0).
// Grid-staged bytes identical to R0 (512 MB) -> isolates the occupancy hypothesis.
__global__ __launch_bounds__(512, 4) void taylor3(
    const float* __restrict__ c3, const float* __restrict__ c2,
    const unsigned short* __restrict__ rel_bf16, float* __restrict__ partial)
{
    __shared__ unsigned short Bs[2][BN * DD];          // 32 KB, double-buffered
    __shared__ unsigned short relIbf[BB];              // 4 KB: rel[:, i_t] bf16
    __shared__ __align__(16) float c2row[BM];          // 512 B: c2[i_t, jbase..+128)
    __shared__ float colsum[2][8][BN];                 // 2 KB, per-wave partials, dbuf

    const int bidx  = blockIdx.x;
    const int i_t   = bidx >> 1;
    const int jbase = (bidx & 1) << 7;
    const int tid  = threadIdx.x;
    const int wave = tid >> 6;
    const int lane = tid & 63;
    const int wm = wave & 1, wk = wave >> 1;           // wm: row half, wk: k quarter
    const int lrow = lane & 15, quad = lane >> 4;

    // stage rel[:, i_t] (bf16) into LDS, one-time
#pragma unroll
    for (int k = 0; k < 4; ++k) {
        const int b = tid + k * 512;
        relIbf[b] = rel_bf16[(size_t)b * DD + i_t];
    }
    if (tid < BM) c2row[tid] = c2[i_t * DD + jbase + tid];

    // ---- hoist A fragments: 64 rows (mt=4) x own 64-k quarter -> 32 VGPRs ----
    bf16x8 afr[2][4];
    {
#pragma unroll
        for (int mt = 0; mt < 4; ++mt) {
            const int j = jbase + wm * 64 + mt * 16 + lrow;
            const float* p = c3 + ((size_t)i_t * DD + j) * DD + wk * 64 + quad * 8;
#pragma unroll
            for (int ks = 0; ks < 2; ++ks) {
                const float4 f0 = *(const float4*)(p + ks * 32);
                const float4 f1 = *(const float4*)(p + ks * 32 + 4);
                union { unsigned short u[8]; bf16x8 v; } cv;
                cv.u[0] = f2bf(f0.x); cv.u[1] = f2bf(f0.y);
                cv.u[2] = f2bf(f0.z); cv.u[3] = f2bf(f0.w);
                cv.u[4] = f2bf(f1.x); cv.u[5] = f2bf(f1.y);
                cv.u[6] = f2bf(f1.z); cv.u[7] = f2bf(f1.w);
                afr[ks][mt] = cv.v;
            }
        }
    }

    // ---- async stage: tile nb -> Bs[buf]; 2 rounds x 16 rows, swizzled granules ----
    auto stage = [&](int nb, int buf) {
        const int b0 = nb * BN;
#pragma unroll
        for (int c = 0; c < 2; ++c) {
            const int r0 = c * 16 + wave * 2;           // wave-uniform base row (0..31)
            const int row = r0 + (lane >> 5);
            const int g = (lane & 31) ^ (row & 7);      // logical granule for this phys slot
            const unsigned short* src = rel_bf16 + (size_t)(b0 + row) * DD + g * 8;
            async_cp16(src, &Bs[buf][r0 * DD]);
        }
    };

    // ---- one pipeline stage; cur is a compile-time literal at each call site ----
    auto body = [&](int nb, int cur) {
        const int b0 = nb * BN;
        __syncthreads();          // drains async loads of Bs[cur]; WAR-protects Bs[cur^1]
        if (nb + 1 < NSTAGE) stage(nb + 1, cur ^ 1);

        // combine previous stage's colsum (parity cur^1); plain coalesced store
        if (nb > 0 && wave == 0 && lane < BN) {
            const int pb0 = b0 - BN;
            float v = colsum[cur ^ 1][0][lane];
#pragma unroll
            for (int w = 1; w < 8; ++w) v += colsum[cur ^ 1][w][lane];
            partial[(size_t)bidx * BB + pb0 + lane] = bf2f(relIbf[pb0 + lane]) * v;
        }

        f32x4 acc[4][2];
        __builtin_amdgcn_s_setprio(1);
        // ---- K-loop: 2 steps of 16x16x32 over this wave's 64-k quarter; ks=0 peeled ----
        {
            bf16x8 bfr[2];
#pragma unroll
            for (int nt = 0; nt < 2; ++nt) {
                const int col = nt * 16 + lrow;
                const int glog = wk * 8 + quad;
                const int g = glog ^ (col & 7);
                bfr[nt] = *(const bf16x8*)(&Bs[cur][col * DD + g * 8]);
            }
            const f32x4 z4 = (f32x4){0.f, 0.f, 0.f, 0.f};
#pragma unroll
            for (int mt = 0; mt < 4; ++mt)
#pragma unroll
                for (int nt = 0; nt < 2; ++nt)
                    acc[mt][nt] = __builtin_amdgcn_mfma_f32_16x16x32_bf16(
                        afr[0][mt], bfr[nt], z4, 0, 0, 0);
        }
        {
            bf16x8 bfr[2];
#pragma unroll
            for (int nt = 0; nt < 2; ++nt) {
                const int col = nt * 16 + lrow;
                const int glog = wk * 8 + 4 + quad;
                const int g = glog ^ (col & 7);
                bfr[nt] = *(const bf16x8*)(&Bs[cur][col * DD + g * 8]);
            }
#pragma unroll
            for (int mt = 0; mt < 4; ++mt)
#pragma unroll
                for (int nt = 0; nt < 2; ++nt)
                    acc[mt][nt] = __builtin_amdgcn_mfma_f32_16x16x32_bf16(
                        afr[1][mt], bfr[nt], acc[mt][nt], 0, 0, 0);
        }
        __builtin_amdgcn_s_setprio(0);

        // ---- epilogue: s(col) = sum_rows (G + c2?) * r[b, j(row)]; indep chains ----
        float sv[2];
#pragma unroll
        for (int nt = 0; nt < 2; ++nt) {
            const int col = nt * 16 + lrow;
            float s0 = 0.f, s1 = 0.f;
#pragma unroll
            for (int mt = 0; mt < 4; ++mt) {
                const int el = wm * 64 + mt * 16 + quad * 4;    // local j (0..127)
                const int e  = jbase + el;                      // global j
                const int g  = (e >> 3) ^ (col & 7);
                const ushort4 rj = *(const ushort4*)(&Bs[cur][col * DD + g * 8 + (e & 7)]);
                f32x4 a = acc[mt][nt];
                if (wk == 0) {   // c2 folded exactly once, wave-uniform branch
                    const float4 c2r = *(const float4*)(&c2row[el]);
                    a[0] += c2r.x; a[1] += c2r.y; a[2] += c2r.z; a[3] += c2r.w;
                }
                float& sa = (mt & 1) ? s1 : s0;   // mt is compile-time constant
                sa = fmaf(a[0], bf2f(rj.x), sa);
                sa = fmaf(a[1], bf2f(rj.y), sa);
                sa = fmaf(a[2], bf2f(rj.z), sa);
                sa = fmaf(a[3], bf2f(rj.w), sa);
            }
            float s = s0 + s1;
            s += __shfl_xor(s, 16, 64);
            s += __shfl_xor(s, 32, 64);   // all lanes hold the column total
            sv[nt] = s;
        }
        // lanes 0..31 write this wave's 32 columns
        if (lane < 32)
            colsum[cur][wave][lane] = (lane & 16) ? sv[1] : sv[0];
    };

    stage(0, 0);
    for (int nb = 0; nb < NSTAGE; nb += 2) {
        body(nb, 0);
        body(nb + 1, 1);
    }

    __syncthreads();
    if (wave == 0 && lane < BN) {   // final combine, parity (NSTAGE-1)&1 = 1
        const int pb0 = BB - BN;
        float v = colsum[1][0][lane];
#pragma unroll
        for (int w = 1; w < 8; ++w) v += colsum[1][w][lane];
        partial[(size_t)bidx * BB + pb0 + lane] = bf2f(relIbf[pb0 + lane]) * v;
    }
}

// K4: out[b] += sum over 512 partial rows. 128 blocks x 256 threads.
__global__ void reduce_partial(const float* __restrict__ partial, float* __restrict__ out) {
    __shared__ f32x4 red[256];
    const int t = threadIdx.x;
    const int g = blockIdx.x * 4 + (t & 3);   // float4 column group (512 total)
    const int slice = t >> 2;                 // 64 row-slices of 8 rows
    f32x4 s = (f32x4){0.f, 0.f, 0.f, 0.f};
    for (int r = slice * 8; r < slice * 8 + 8; ++r)
        s += *(const f32x4*)(partial + (size_t)r * BB + g * 4);
    red[t] = s; __syncthreads();
    if (t < 128) red[t] += red[t + 128]; __syncthreads();
    if (t < 64)  red[t] += red[t + 64];  __syncthreads();
    if (t < 32)  red[t] += red[t + 32];  __syncthreads();
    if (t < 16)  red[t] += red[t + 16];  __syncthreads();
    if (t < 8)   red[t] += red[t + 8];   __syncthreads();
    if (t < 4) {
        const f32x4 v = red[t] + red[t + 4];
        float4* op = (float4*)(out + (size_t)(blockIdx.x * 4 + t) * 4);
        float4 o = *op;
        o.x += v[0]; o.y += v[1]; o.z += v[2]; o.w += v[3];
        *op = o;
    }
}

extern "C" void kernel_launch(void* const* d_in, const int* in_sizes, int n_in,
                              void* d_out, int out_size, void* d_ws, size_t ws_size,
                              hipStream_t stream) {
    const float* x       = (const float*)d_in[0];
    const float* offsets = (const float*)d_in[1];
    const float* c0      = (const float*)d_in[2];
    const float* c1      = (const float*)d_in[3];
    const float* c2      = (const float*)d_in[4];
    const float* c3      = (const float*)d_in[5];
    float* out = (float*)d_out;

    char* ws = (char*)d_ws;
    unsigned short* rel_bf16 = (unsigned short*)ws;                      // 1 MB
    float* partial = (float*)(ws + (size_t)1 * 1024 * 1024);             // 4 MB (512 x 2048)

    prep_all<<<BB / 8, 256, 0, stream>>>(x, offsets, c0, c1, rel_bf16, out);
    taylor3<<<NTILE, 512, 0, stream>>>(c3, c2, rel_bf16, partial);
    reduce_partial<<<128, 256, 0, stream>>>(partial, out);
}